// Round 15
// baseline (823.838 us; speedup 1.0000x reference)
//
#include <hip/hip_runtime.h>
#include <stdint.h>

typedef unsigned short u16;
typedef __attribute__((ext_vector_type(8))) short bf16x8;
typedef __attribute__((ext_vector_type(4))) float f32x4;
typedef __attribute__((ext_vector_type(16))) float f32x16;
typedef __attribute__((ext_vector_type(2))) unsigned int u32x2;
typedef __attribute__((ext_vector_type(4))) unsigned int u32x4;

__device__ __forceinline__ float bf2f(u16 u) {
  union { unsigned int i; float f; } v; v.i = ((unsigned int)u) << 16; return v.f;
}
__device__ __forceinline__ u16 f2bf(float f) {
  union { float f; unsigned int i; } v; v.f = f;
  unsigned int x = v.i;
  return (u16)((x + 0x7fffu + ((x >> 16) & 1u)) >> 16);  // RNE
}

__device__ __forceinline__ void async16(const void* g, void* l) {
  __builtin_amdgcn_global_load_lds(
      (const __attribute__((address_space(1))) void*)g,
      (__attribute__((address_space(3))) void*)l, 16, 0, 0);
}

// ---------------------------------------------------------------- casts ----
__global__ __launch_bounds__(256) void cast_f32_to_bf16(
    const float* __restrict__ x, u16* __restrict__ y, long n) {
  long i = ((long)blockIdx.x * blockDim.x + threadIdx.x) * 8;
  long stride = (long)gridDim.x * blockDim.x * 8;
  for (long j = i; j < n; j += stride) {
    float4 a = ((const float4*)(x + j))[0];
    float4 b = ((const float4*)(x + j))[1];
    u32x4 o;
    o.x = (unsigned)f2bf(a.x) | ((unsigned)f2bf(a.y) << 16);
    o.y = (unsigned)f2bf(a.z) | ((unsigned)f2bf(a.w) << 16);
    o.z = (unsigned)f2bf(b.x) | ((unsigned)f2bf(b.y) << 16);
    o.w = (unsigned)f2bf(b.z) | ((unsigned)f2bf(b.w) << 16);
    __builtin_nontemporal_store(o, (u32x4*)(y + j));
  }
}

// bf16 [32][2048][512] -> bf16 [32][512][2048] (tile transpose)
__global__ __launch_bounds__(256) void transB(
    const u16* __restrict__ src, u16* __restrict__ dst) {
  __shared__ u16 tile[32][34];
  int t = threadIdx.x;
  long b = blockIdx.z;
  int n0 = blockIdx.x * 32, c0 = blockIdx.y * 32;
  int nr = t >> 3, c4 = (t & 7) * 4;
  u32x2 v = *(const u32x2*)(src + (b * 2048 + n0 + nr) * 512 + c0 + c4);
  tile[nr][c4]     = (u16)(v.x & 0xffffu);
  tile[nr][c4 + 1] = (u16)(v.x >> 16);
  tile[nr][c4 + 2] = (u16)(v.y & 0xffffu);
  tile[nr][c4 + 3] = (u16)(v.y >> 16);
  __syncthreads();
  int cr = t >> 3, n4 = (t & 7) * 4;
  unsigned r0 = tile[n4][cr], r1 = tile[n4 + 1][cr];
  unsigned r2 = tile[n4 + 2][cr], r3 = tile[n4 + 3][cr];
  u32x2 o; o.x = r0 | (r1 << 16); o.y = r2 | (r3 << 16);
  __builtin_nontemporal_store(o, (u32x2*)(dst + (b * 512 + c0 + cr) * 2048 + n0 + n4));
}

// ------------------------------------------------- small weight kernels ----
__global__ __launch_bounds__(256) void smallGT(
    const float* __restrict__ Ai, const float* __restrict__ Bi, u16* __restrict__ C) {
  __shared__ float As[16][65], Bs[16][65];
  int t = threadIdx.x;
  int i0 = blockIdx.y * 16, j0 = blockIdx.x * 16;
  int r = t >> 4, c4 = (t & 15) * 4;
  int ty = t >> 4, tx = t & 15;
  float acc = 0.f;
  for (int d0 = 0; d0 < 512; d0 += 64) {
    float4 a = *(const float4*)(Ai + (i0 + r) * 512 + d0 + c4);
    float4 b = *(const float4*)(Bi + (j0 + r) * 512 + d0 + c4);
    __syncthreads();
    As[r][c4] = a.x; As[r][c4 + 1] = a.y; As[r][c4 + 2] = a.z; As[r][c4 + 3] = a.w;
    Bs[r][c4] = b.x; Bs[r][c4 + 1] = b.y; Bs[r][c4 + 2] = b.z; Bs[r][c4 + 3] = b.w;
    __syncthreads();
#pragma unroll
    for (int d = 0; d < 64; ++d) acc += As[ty][d] * Bs[tx][d];
  }
  C[(i0 + ty) * 512 + j0 + tx] = f2bf(acc);
}

__global__ __launch_bounds__(256) void smallW2T(
    const float* __restrict__ Wv, const float* __restrict__ Wo, u16* __restrict__ C) {
  __shared__ float Vs[16][65];
  __shared__ float Os[64][17];
  int t = threadIdx.x;
  int k0 = blockIdx.x * 16, n0 = blockIdx.y * 16;
  int r = t >> 4, c4 = (t & 15) * 4;
  int dd = t >> 2, nn4 = (t & 3) * 4;
  int ty = t >> 4, tx = t & 15;
  float acc = 0.f;
  for (int d0 = 0; d0 < 512; d0 += 64) {
    float4 a = *(const float4*)(Wv + (k0 + r) * 512 + d0 + c4);
    float4 b = *(const float4*)(Wo + (long)(d0 + dd) * 512 + n0 + nn4);
    __syncthreads();
    Vs[r][c4] = a.x; Vs[r][c4 + 1] = a.y; Vs[r][c4 + 2] = a.z; Vs[r][c4 + 3] = a.w;
    Os[dd][nn4] = b.x; Os[dd][nn4 + 1] = b.y; Os[dd][nn4 + 2] = b.z; Os[dd][nn4 + 3] = b.w;
    __syncthreads();
#pragma unroll
    for (int d = 0; d < 64; ++d) acc += Vs[tx][d] * Os[d][ty];
  }
  C[(n0 + ty) * 512 + k0 + tx] = f2bf(acc);
}

__global__ __launch_bounds__(256) void wveck(
    const float* __restrict__ Wk, const float* __restrict__ bq, float* __restrict__ wv) {
  int c = blockIdx.x, t = threadIdx.x;
  float s = 0.f;
  for (int d = t; d < 512; d += 256) s += Wk[c * 512 + d] * bq[d];
  for (int off = 32; off; off >>= 1) s += __shfl_xor(s, off);
  __shared__ float r4[4];
  if ((t & 63) == 0) r4[t >> 6] = s;
  __syncthreads();
  if (t == 0) wv[c] = (r4[0] + r4[1] + r4[2] + r4[3]) * (1.0f / 512.0f);
}

__global__ __launch_bounds__(256) void cveck(
    const float* __restrict__ Wo, const float* __restrict__ bv,
    const float* __restrict__ bo, float* __restrict__ c2) {
  int e = blockIdx.x * 256 + threadIdx.x;
  float s = 0.f;
  for (int d = 0; d < 512; ++d) s += bv[d] * Wo[d * 512 + e];
  c2[e] = s * (1.0f / 2048.0f) + bo[e];
}

__global__ __launch_bounds__(256) void betak(
    const u16* __restrict__ Kb, const float* __restrict__ wv, float* __restrict__ beta) {
  __shared__ float ws[512];
  int t = threadIdx.x, lane = t & 63, wid = t >> 6;
  ws[t] = wv[t];
  ws[t + 256] = wv[t + 256];
  __syncthreads();
  long row = (long)blockIdx.x * 4 + wid;
  bf16x8 v = *(const bf16x8*)(Kb + row * 512 + lane * 8);
  float s = 0.f;
#pragma unroll
  for (int j = 0; j < 8; ++j) s += bf2f((u16)v[j]) * ws[lane * 8 + j];
  for (int off = 32; off; off >>= 1) s += __shfl_xor(s, off);
  if (lane == 0) beta[row] = s;
}

// rinv[r] = 1 / sum_{j<32} psum[r*32+j]
__global__ __launch_bounds__(256) void rowred(
    const float* __restrict__ psum, float* __restrict__ rinv, int nrows) {
  int r = blockIdx.x * 256 + threadIdx.x;
  if (r >= nrows) return;
  const float* p = psum + (long)r * 32;
  float s = 0.f;
#pragma unroll
  for (int j = 0; j < 32; ++j) s += p[j];
  rinv[r] = 1.0f / s;
}

// --------------------------------------------------- 256x128 4-wave gemm ----
// R14 + fixed swizzle. 32x32x16 MFMA; per wave 128x64 out = 4x2 grid,
// acc f32x16. Swizzle now SW(r)=((r>>1)^(r>>3))&3 so rows {r,r+8,r+16,r+24}
// (which alias to the same bank at 64B stride) land in 4 distinct 16B slots
// -> conflict-free 32-row fragment reads. Staging inverse matches:
// chunk(l,w) = (l&3)^((l>>3)&3)^(((l>>5)&1)|((w&1)<<1)).
// BK=32, 2-buf LDS, one __syncthreads/tile, 3 blocks/CU, XCD-pinned decode.
// EXPO=1: exp + psum row partials. rsc: row scale.
template <int MODE, int EXPO>
__global__ __launch_bounds__(256, 3) void gemm(
    const u16* __restrict__ A, const u16* __restrict__ B,
    const float* __restrict__ bias, long sBias,
    const float* __restrict__ rsc, float* __restrict__ psum,
    void* __restrict__ Cout,
    int N, int K, long sA, long sB, long sC, float scale,
    int mT, int nT, int Z, int nfast) {
  __shared__ __align__(16) char lds[2][24576];  // per buf: A 16K | B 8K
  const int t = threadIdx.x;
  const int lane = t & 63;
  const int w = t >> 6;        // 0..3
  const int wm = w >> 1;       // 0..1 (row half)
  const int wn = w & 1;        // 0..1 (col half)

  // ---- block decode (XCD pin when Z%8==0) ----
  const int wg = blockIdx.x;
  const int nb = mT * nT;
  long z; int within;
  if (Z > 1 && (Z & 7) == 0) {
    int xcd = wg & 7, sub = wg >> 3;
    z = (long)(sub / nb) * 8 + xcd;
    within = sub % nb;
  } else { z = wg / nb; within = wg % nb; }
  int bx, by;
  if (nfast) { by = within % nT; bx = within / nT; }
  else       { bx = within % mT; by = within / mT; }
  const long m0 = (long)bx * 256;
  const int n0 = by * 128;
  const int nt = K >> 5;

  // staging: linear LDS dest, inverse-swizzled global source.
  // lane l writes LDS row (base + l>>2), slot l&3; global chunk must be
  // (l&3) ^ SW(row) where SW(row)=((row>>1)^(row>>3))&3;
  // row bits 1-2 = (l>>3)&3, bits 3-4 = ((l>>5)&1) | ((w&1)<<1).
  const int srow = w * 16 + (lane >> 2);
  const int koff = 8 * ((lane & 3) ^ ((lane >> 3) & 3) ^
                        (((lane >> 5) & 1) | ((w & 1) << 1)));
  const u16* pa = A + z * sA + (m0 + srow) * (long)K + koff;
  const u16* pb = B + z * sB + ((long)(n0 + srow)) * K + koff;
  const int ldsW = w * 1024;

  // reads: swizzled ds_read_b128, 32x32 fragment geometry
  const int r31 = lane & 31;
  const int kh = lane >> 5;                       // k-half 0/1
  const int sw = (((r31 >> 1) ^ (r31 >> 3)) & 3) << 4;
  const int abase = (wm * 128 + r31) * 64;        // + mi*2048 + slot
  const int bbase = 16384 + (wn * 64 + r31) * 64; // + ni*2048 + slot

  f32x16 acc[4][2] = {};

#define STAGE(BUF)                                                         \
  do {                                                                     \
    char* d_ = lds[BUF] + ldsW;                                            \
    _Pragma("unroll") for (int c = 0; c < 4; ++c)                          \
        async16(pa + (long)c * 64 * K, d_ + c * 4096);                     \
    _Pragma("unroll") for (int c = 0; c < 2; ++c)                          \
        async16(pb + (long)c * 64 * K, d_ + 16384 + c * 4096);             \
    pa += 32; pb += 32;                                                    \
  } while (0)

  // prologue: stage tile 0 -> buf 0
  STAGE(0);
  __syncthreads();

  int cur = 0;
  for (int tt = 0; tt < nt; ++tt) {
    if (tt + 1 < nt) STAGE(cur ^ 1);
    const char* rb = lds[cur];
    bf16x8 bfr[2][2];  // [kstep][ni]
#pragma unroll
    for (int ks = 0; ks < 2; ++ks)
#pragma unroll
      for (int ni = 0; ni < 2; ++ni)
        bfr[ks][ni] = *(const bf16x8*)(rb + bbase + ni * 2048 +
                                       (((ks * 2 + kh) * 16) ^ sw));
    __builtin_amdgcn_s_setprio(1);
#pragma unroll
    for (int mi = 0; mi < 4; ++mi) {
      bf16x8 a0 = *(const bf16x8*)(rb + abase + mi * 2048 + ((kh * 16) ^ sw));
      bf16x8 a1 = *(const bf16x8*)(rb + abase + mi * 2048 + (((2 + kh) * 16) ^ sw));
#pragma unroll
      for (int ni = 0; ni < 2; ++ni) {
        acc[mi][ni] = __builtin_amdgcn_mfma_f32_32x32x16_bf16(
            a0, bfr[0][ni], acc[mi][ni], 0, 0, 0);
        acc[mi][ni] = __builtin_amdgcn_mfma_f32_32x32x16_bf16(
            a1, bfr[1][ni], acc[mi][ni], 0, 0, 0);
      }
    }
    __builtin_amdgcn_s_setprio(0);
    __syncthreads();
    cur ^= 1;
  }
#undef STAGE

  // ---- epilogue (C/D: col=lane&31, row=(reg&3)+8*(reg>>2)+4*kh) ----
  float bvv[2];
#pragma unroll
  for (int ni = 0; ni < 2; ++ni)
    bvv[ni] = bias ? bias[z * sBias + n0 + wn * 64 + ni * 32 + r31] : 0.0f;
  if (MODE == 0) {
    // bf16 coalesced via LDS transpose: 2 passes x 128 rows, stride 136 u16
    u16* Ep = (u16*)lds;
    u16* Cp = (u16*)Cout + z * sC;
#pragma unroll
    for (int p = 0; p < 2; ++p) {
      __syncthreads();
      if (wm == p) {
#pragma unroll
        for (int mi = 0; mi < 4; ++mi) {
#pragma unroll
          for (int reg = 0; reg < 16; ++reg) {
            int lrow = mi * 32 + (reg & 3) + 8 * (reg >> 2) + 4 * kh;
            float rv = 1.0f;
            if (!EXPO && rsc) rv = rsc[z * 2048 + m0 + wm * 128 + lrow];
            float rs = 0.f;
#pragma unroll
            for (int ni = 0; ni < 2; ++ni) {
              float val = acc[mi][ni][reg] * scale + bvv[ni];
              if (EXPO) { val = __expf(val); rs += val; }
              else val *= rv;
              Ep[lrow * 136 + wn * 64 + ni * 32 + r31] = f2bf(val);
            }
            if (EXPO) {
              rs += __shfl_xor(rs, 1);
              rs += __shfl_xor(rs, 2);
              rs += __shfl_xor(rs, 4);
              rs += __shfl_xor(rs, 8);
              rs += __shfl_xor(rs, 16);
              if (r31 == 0)
                psum[((long)z * 2048 + m0 + wm * 128 + lrow) * 32 + by * 2 + wn] = rs;
            }
          }
        }
      }
      __syncthreads();
#pragma unroll
      for (int s = 0; s < 8; ++s) {
        int idx = s * 256 + t;
        int R = idx >> 4;   // 0..127
        int j = idx & 15;
        u32x4 d = *(const u32x4*)(Ep + R * 136 + j * 8);
        __builtin_nontemporal_store(
            d, (u32x4*)(Cp + (m0 + p * 128 + R) * (long)N + n0 + j * 8));
      }
    }
  } else {
    // fp32 coalesced via LDS transpose: 4 passes x 64 rows, stride 132 f32
    float* Ep = (float*)lds;
    float* Cp = (float*)Cout + z * sC;
#pragma unroll
    for (int p = 0; p < 4; ++p) {
      __syncthreads();
      if (wm == (p >> 1)) {
#pragma unroll
        for (int mi2 = 0; mi2 < 2; ++mi2) {
          int mi = (p & 1) * 2 + mi2;
#pragma unroll
          for (int reg = 0; reg < 16; ++reg) {
            int crow = (reg & 3) + 8 * (reg >> 2) + 4 * kh;
            int lrow = mi2 * 32 + crow;          // within this 64-row pass
            int grow = mi * 32 + crow;           // within the 128-row half
            float rv = 1.0f;
            if (rsc) rv = rsc[z * 2048 + m0 + wm * 128 + grow];
#pragma unroll
            for (int ni = 0; ni < 2; ++ni)
              Ep[lrow * 132 + wn * 64 + ni * 32 + r31] =
                  acc[mi][ni][reg] * scale * rv + bvv[ni];
          }
        }
      }
      __syncthreads();
#pragma unroll
      for (int s = 0; s < 8; ++s) {
        int idx = s * 256 + t;
        int R = idx >> 5;   // 0..63
        int j = idx & 31;   // 0..31
        f32x4 d = *(const f32x4*)(Ep + R * 132 + j * 4);
        __builtin_nontemporal_store(
            d, (f32x4*)(Cp + (m0 + p * 64 + R) * (long)N + n0 + j * 4));
      }
    }
  }
}

// -------------------------------------------------------------- launch ----
extern "C" void kernel_launch(void* const* d_in, const int* in_sizes, int n_in,
                              void* d_out, int out_size, void* d_ws, size_t ws_size,
                              hipStream_t stream) {
  const float* query = (const float*)d_in[0];
  const float* key_  = (const float*)d_in[1];
  const float* Wq = (const float*)d_in[2];
  const float* bq = (const float*)d_in[3];
  const float* Wk = (const float*)d_in[4];
  const float* bk = (const float*)d_in[5];  // row-constant in scores: cancels
  const float* Wv = (const float*)d_in[6];
  const float* bv = (const float*)d_in[7];
  const float* Wo = (const float*)d_in[8];
  const float* bo = (const float*)d_in[9];
  (void)bk;
  float* out = (float*)d_out;

  const long tokE = 65536L * 512;
  const long bstride = 2048L * 512;

  // ws layout: Kb 0-64M | V2T 64-128M | qb 128-192M | weights/vecs | S
  char* ws = (char*)d_ws;
  u16* Kb   = (u16*)(ws);                     // 64 MB
  u16* V2T  = (u16*)(ws + 67108864L);         // 64 MB, per batch [512][2048]
  u16* qb   = (u16*)(ws + 134217728L);        // 64 MB
  u16* GT   = (u16*)(ws + 201326592L);        // 0.5 MB
  u16* W2T  = (u16*)(ws + 201850880L);        // 0.5 MB
  float* wv   = (float*)(ws + 202375168L);    // 2 KB
  float* c2   = (float*)(ws + 202377216L);    // 2 KB
  float* beta = (float*)(ws + 202379264L);    // 256 KB
  float* rinv = (float*)(ws + 202641408L);    // 256 KB
  char* Sbase = ws + 202903552L;

  // d_out time-share: Qb/V2tmp [0:64M) until consumed; psum [64:72M) per
  // group until rowred; PV2 writes all of d_out last (final output).
  u16* Qb = (u16*)d_out;
  u16* V2tmp = (u16*)d_out;
  float* psum = (float*)((char*)d_out + 67108864L);

  long s_avail = (long)ws_size - 202903552L;
  int g = (int)(s_avail / 8388608L);
  if (g < 1) g = 1;
  if (g > 32) g = 32;
  if (g >= 8) g &= ~7;  // batches/dispatch multiple of 8 (XCD pin)

  // 1. casts + fused weights
  cast_f32_to_bf16<<<16384, 256, 0, stream>>>(query, Qb, tokE);
  cast_f32_to_bf16<<<16384, 256, 0, stream>>>(key_, Kb, tokE);
  smallGT<<<dim3(32, 32), 256, 0, stream>>>(Wk, Wq, GT);    // GT[n,c] = WkWq^T
  smallW2T<<<dim3(32, 32), 256, 0, stream>>>(Wv, Wo, W2T);  // W2T[e,k] = (WvWo)^T
  wveck<<<512, 256, 0, stream>>>(Wk, bq, wv);
  cveck<<<2, 256, 0, stream>>>(Wo, bv, bo, c2);
  betak<<<16384, 256, 0, stream>>>(Kb, wv, beta);

  // 2. q' = Q @ (Wq Wk^T)   [65536 x 512]   (frees Qb region afterwards)
  gemm<0, 0><<<256 * 4, 256, 0, stream>>>(
      Qb, GT, nullptr, 0, nullptr, nullptr, qb,
      512, 512, 0, 0, 0, 1.0f, 256, 4, 1, 0);

  // 3. V2 = Kb @ (Wv Wo)  [65536 x 512] into d_out scratch, then transpose
  gemm<0, 0><<<256 * 4, 256, 0, stream>>>(
      Kb, W2T, nullptr, 0, nullptr, nullptr, V2tmp,
      512, 512, 0, 0, 0, 1.0f, 256, 4, 1, 0);
  transB<<<dim3(64, 16, 32), 256, 0, stream>>>(V2tmp, V2T);

  // 4. attention per group:
  //    E = exp(q'.Kb^T/512 + beta) + row partials ; rinv = 1/rowsum ;
  //    out = E.V2 * rinv/2048 + c2   (fp32, final)
  for (int b0 = 0; b0 < 32; b0 += g) {
    int bc = (32 - b0 < g) ? (32 - b0) : g;
    u16* Sg = (u16*)Sbase;
    gemm<0, 1><<<8 * 16 * bc, 256, 0, stream>>>(
        qb + (long)b0 * bstride, Kb + (long)b0 * bstride,
        beta + (long)b0 * 2048, 2048, nullptr, psum, Sg, 2048, 512,
        bstride, bstride, 2048L * 2048, 1.0f / 512.0f, 8, 16, bc, 0);
    rowred<<<(bc * 2048 + 255) / 256, 256, 0, stream>>>(psum, rinv, bc * 2048);
    gemm<2, 0><<<8 * 4 * bc, 256, 0, stream>>>(
        Sg, V2T + (long)b0 * bstride, c2, 0, rinv, nullptr,
        out + (long)b0 * bstride, 512, 2048,
        2048L * 2048, bstride, bstride, 1.0f / 2048.0f, 8, 4, bc, 1);
  }
}

// Round 16
// 695.781 us; speedup vs baseline: 1.1840x; 1.1840x over previous
//
#include <hip/hip_runtime.h>
#include <stdint.h>

typedef unsigned short u16;
typedef __attribute__((ext_vector_type(8))) short bf16x8;
typedef __attribute__((ext_vector_type(4))) float f32x4;
typedef __attribute__((ext_vector_type(2))) unsigned int u32x2;
typedef __attribute__((ext_vector_type(4))) unsigned int u32x4;

__device__ __forceinline__ float bf2f(u16 u) {
  union { unsigned int i; float f; } v; v.i = ((unsigned int)u) << 16; return v.f;
}
__device__ __forceinline__ u16 f2bf(float f) {
  union { float f; unsigned int i; } v; v.f = f;
  unsigned int x = v.i;
  return (u16)((x + 0x7fffu + ((x >> 16) & 1u)) >> 16);  // RNE
}

__device__ __forceinline__ void async16(const void* g, void* l) {
  __builtin_amdgcn_global_load_lds(
      (const __attribute__((address_space(1))) void*)g,
      (__attribute__((address_space(3))) void*)l, 16, 0, 0);
}

// ---------------------------------------------------------------- casts ----
__global__ __launch_bounds__(256) void cast_f32_to_bf16(
    const float* __restrict__ x, u16* __restrict__ y, long n) {
  long i = ((long)blockIdx.x * blockDim.x + threadIdx.x) * 8;
  long stride = (long)gridDim.x * blockDim.x * 8;
  for (long j = i; j < n; j += stride) {
    float4 a = ((const float4*)(x + j))[0];
    float4 b = ((const float4*)(x + j))[1];
    u32x4 o;
    o.x = (unsigned)f2bf(a.x) | ((unsigned)f2bf(a.y) << 16);
    o.y = (unsigned)f2bf(a.z) | ((unsigned)f2bf(a.w) << 16);
    o.z = (unsigned)f2bf(b.x) | ((unsigned)f2bf(b.y) << 16);
    o.w = (unsigned)f2bf(b.z) | ((unsigned)f2bf(b.w) << 16);
    __builtin_nontemporal_store(o, (u32x4*)(y + j));
  }
}

// key f32 -> Kb bf16, fused beta[row] = dot(bf16(keyrow), wv)  (wv has /512)
// one wave per row: 512 f32 = 8/lane
__global__ __launch_bounds__(256) void castK_beta(
    const float* __restrict__ Kin, const float* __restrict__ wvec,
    u16* __restrict__ Kb, float* __restrict__ beta) {
  __shared__ float ws[512];
  int t = threadIdx.x, lane = t & 63, wid = t >> 6;
  ws[t] = wvec[t];
  ws[t + 256] = wvec[t + 256];
  __syncthreads();
  long row = (long)blockIdx.x * 4 + wid;
  const float* src = Kin + row * 512 + lane * 8;
  float4 a = *(const float4*)(src);
  float4 b = *(const float4*)(src + 4);
  unsigned q0 = f2bf(a.x), q1 = f2bf(a.y), q2 = f2bf(a.z), q3 = f2bf(a.w);
  unsigned q4 = f2bf(b.x), q5 = f2bf(b.y), q6 = f2bf(b.z), q7 = f2bf(b.w);
  u32x4 o;
  o.x = q0 | (q1 << 16);
  o.y = q2 | (q3 << 16);
  o.z = q4 | (q5 << 16);
  o.w = q6 | (q7 << 16);
  __builtin_nontemporal_store(o, (u32x4*)(Kb + row * 512 + lane * 8));
  const float* w8 = ws + lane * 8;
  float s = bf2f((u16)q0) * w8[0] + bf2f((u16)q1) * w8[1] +
            bf2f((u16)q2) * w8[2] + bf2f((u16)q3) * w8[3] +
            bf2f((u16)q4) * w8[4] + bf2f((u16)q5) * w8[5] +
            bf2f((u16)q6) * w8[6] + bf2f((u16)q7) * w8[7];
  for (int off = 32; off; off >>= 1) s += __shfl_xor(s, off);
  if (lane == 0) beta[row] = s;
}

// bf16 [32][2048][512] -> bf16 [32][512][2048] (tile transpose)
__global__ __launch_bounds__(256) void transB(
    const u16* __restrict__ src, u16* __restrict__ dst) {
  __shared__ u16 tile[32][34];
  int t = threadIdx.x;
  long b = blockIdx.z;
  int n0 = blockIdx.x * 32, c0 = blockIdx.y * 32;
  int nr = t >> 3, c4 = (t & 7) * 4;
  u32x2 v = *(const u32x2*)(src + (b * 2048 + n0 + nr) * 512 + c0 + c4);
  tile[nr][c4]     = (u16)(v.x & 0xffffu);
  tile[nr][c4 + 1] = (u16)(v.x >> 16);
  tile[nr][c4 + 2] = (u16)(v.y & 0xffffu);
  tile[nr][c4 + 3] = (u16)(v.y >> 16);
  __syncthreads();
  int cr = t >> 3, n4 = (t & 7) * 4;
  unsigned r0 = tile[n4][cr], r1 = tile[n4 + 1][cr];
  unsigned r2 = tile[n4 + 2][cr], r3 = tile[n4 + 3][cr];
  u32x2 o; o.x = r0 | (r1 << 16); o.y = r2 | (r3 << 16);
  __builtin_nontemporal_store(o, (u32x2*)(dst + (b * 512 + c0 + cr) * 2048 + n0 + n4));
}

// ------------------------------------------------- small weight kernels ----
__global__ __launch_bounds__(256) void smallGT(
    const float* __restrict__ Ai, const float* __restrict__ Bi, u16* __restrict__ C) {
  __shared__ float As[16][65], Bs[16][65];
  int t = threadIdx.x;
  int i0 = blockIdx.y * 16, j0 = blockIdx.x * 16;
  int r = t >> 4, c4 = (t & 15) * 4;
  int ty = t >> 4, tx = t & 15;
  float acc = 0.f;
  for (int d0 = 0; d0 < 512; d0 += 64) {
    float4 a = *(const float4*)(Ai + (i0 + r) * 512 + d0 + c4);
    float4 b = *(const float4*)(Bi + (j0 + r) * 512 + d0 + c4);
    __syncthreads();
    As[r][c4] = a.x; As[r][c4 + 1] = a.y; As[r][c4 + 2] = a.z; As[r][c4 + 3] = a.w;
    Bs[r][c4] = b.x; Bs[r][c4 + 1] = b.y; Bs[r][c4 + 2] = b.z; Bs[r][c4 + 3] = b.w;
    __syncthreads();
#pragma unroll
    for (int d = 0; d < 64; ++d) acc += As[ty][d] * Bs[tx][d];
  }
  C[(i0 + ty) * 512 + j0 + tx] = f2bf(acc);
}

__global__ __launch_bounds__(256) void smallW2T(
    const float* __restrict__ Wv, const float* __restrict__ Wo, u16* __restrict__ C) {
  __shared__ float Vs[16][65];
  __shared__ float Os[64][17];
  int t = threadIdx.x;
  int k0 = blockIdx.x * 16, n0 = blockIdx.y * 16;
  int r = t >> 4, c4 = (t & 15) * 4;
  int dd = t >> 2, nn4 = (t & 3) * 4;
  int ty = t >> 4, tx = t & 15;
  float acc = 0.f;
  for (int d0 = 0; d0 < 512; d0 += 64) {
    float4 a = *(const float4*)(Wv + (k0 + r) * 512 + d0 + c4);
    float4 b = *(const float4*)(Wo + (long)(d0 + dd) * 512 + n0 + nn4);
    __syncthreads();
    Vs[r][c4] = a.x; Vs[r][c4 + 1] = a.y; Vs[r][c4 + 2] = a.z; Vs[r][c4 + 3] = a.w;
    Os[dd][nn4] = b.x; Os[dd][nn4 + 1] = b.y; Os[dd][nn4 + 2] = b.z; Os[dd][nn4 + 3] = b.w;
    __syncthreads();
#pragma unroll
    for (int d = 0; d < 64; ++d) acc += Vs[tx][d] * Os[d][ty];
  }
  C[(n0 + ty) * 512 + k0 + tx] = f2bf(acc);
}

__global__ __launch_bounds__(256) void wveck(
    const float* __restrict__ Wk, const float* __restrict__ bq, float* __restrict__ wv) {
  int c = blockIdx.x, t = threadIdx.x;
  float s = 0.f;
  for (int d = t; d < 512; d += 256) s += Wk[c * 512 + d] * bq[d];
  for (int off = 32; off; off >>= 1) s += __shfl_xor(s, off);
  __shared__ float r4[4];
  if ((t & 63) == 0) r4[t >> 6] = s;
  __syncthreads();
  if (t == 0) wv[c] = (r4[0] + r4[1] + r4[2] + r4[3]) * (1.0f / 512.0f);
}

__global__ __launch_bounds__(256) void cveck(
    const float* __restrict__ Wo, const float* __restrict__ bv,
    const float* __restrict__ bo, float* __restrict__ c2) {
  int e = blockIdx.x * 256 + threadIdx.x;
  float s = 0.f;
  for (int d = 0; d < 512; ++d) s += bv[d] * Wo[d * 512 + e];
  c2[e] = s * (1.0f / 2048.0f) + bo[e];
}

// rinv[r] = 1 / sum_{j<32} psum[r*32+j]
__global__ __launch_bounds__(256) void rowred(
    const float* __restrict__ psum, float* __restrict__ rinv, int nrows) {
  int r = blockIdx.x * 256 + threadIdx.x;
  if (r >= nrows) return;
  const float* p = psum + (long)r * 32;
  float s = 0.f;
#pragma unroll
  for (int j = 0; j < 32; ++j) s += p[j];
  rinv[r] = 1.0f / s;
}

// --------------------------------------------------- 256x128 4-wave gemm ----
// R13 (measured best): 16x16x32 MFMA, BK=32, 2-buf LDS, one __syncthreads per
// tile, 3 blocks/CU, XCD-pinned decode, swizzle byte^=((row>>1)&3)<<4
// (conflict-free, verified). EXPO=1: epilogue exp(val) + partial row sums ->
// psum[.][32]. rsc: per-row scale (MODE 0 and MODE 2 epilogues).
template <int MODE, int EXPO>
__global__ __launch_bounds__(256, 3) void gemm(
    const u16* __restrict__ A, const u16* __restrict__ B,
    const float* __restrict__ bias, long sBias,
    const float* __restrict__ rsc, float* __restrict__ psum,
    void* __restrict__ Cout,
    int N, int K, long sA, long sB, long sC, float scale,
    int mT, int nT, int Z, int nfast) {
  __shared__ __align__(16) char lds[2][24576];  // per buf: A 16K | B 8K
  const int t = threadIdx.x;
  const int lane = t & 63;
  const int w = t >> 6;        // 0..3
  const int wm = w >> 1;       // 0..1 (row half)
  const int wn = w & 1;        // 0..1 (col half)

  // ---- block decode (XCD pin when Z%8==0) ----
  const int wg = blockIdx.x;
  const int nb = mT * nT;
  long z; int within;
  if (Z > 1 && (Z & 7) == 0) {
    int xcd = wg & 7, sub = wg >> 3;
    z = (long)(sub / nb) * 8 + xcd;
    within = sub % nb;
  } else { z = wg / nb; within = wg % nb; }
  int bx, by;
  if (nfast) { by = within % nT; bx = within / nT; }
  else       { bx = within % mT; by = within / mT; }
  const long m0 = (long)bx * 256;
  const int n0 = by * 128;
  const int nt = K >> 5;

  // staging: linear LDS dest, inverse-swizzled global source
  const int srow = w * 16 + (lane >> 2);
  const int koff = 8 * ((lane & 3) ^ ((lane >> 3) & 3));
  const u16* pa = A + z * sA + (m0 + srow) * (long)K + koff;
  const u16* pb = B + z * sB + ((long)(n0 + srow)) * K + koff;
  const int ldsW = w * 1024;

  // reads: swizzled ds_read_b128
  const int fr = lane & 15;
  const int kb = (lane >> 4) * 16;
  const int sw = ((fr >> 1) & 3) << 4;
  const int aoff = (wm * 128 + fr) * 64 + (kb ^ sw);
  const int boff = 16384 + (wn * 64 + fr) * 64 + (kb ^ sw);

  f32x4 acc[8][4] = {};

#define STAGE(BUF)                                                         \
  do {                                                                     \
    char* d_ = lds[BUF] + ldsW;                                            \
    _Pragma("unroll") for (int c = 0; c < 4; ++c)                          \
        async16(pa + (long)c * 64 * K, d_ + c * 4096);                     \
    _Pragma("unroll") for (int c = 0; c < 2; ++c)                          \
        async16(pb + (long)c * 64 * K, d_ + 16384 + c * 4096);             \
    pa += 32; pb += 32;                                                    \
  } while (0)

  // prologue: stage tile 0 -> buf 0
  STAGE(0);
  __syncthreads();

  int cur = 0;
  for (int tt = 0; tt < nt; ++tt) {
    if (tt + 1 < nt) STAGE(cur ^ 1);
    const char* rb = lds[cur];
    bf16x8 bf[4];
#pragma unroll
    for (int ni = 0; ni < 4; ++ni)
      bf[ni] = *(const bf16x8*)(rb + boff + ni * 1024);
    __builtin_amdgcn_s_setprio(1);
#pragma unroll
    for (int mi = 0; mi < 8; ++mi) {
      bf16x8 af = *(const bf16x8*)(rb + aoff + mi * 1024);
#pragma unroll
      for (int ni = 0; ni < 4; ++ni)
        acc[mi][ni] = __builtin_amdgcn_mfma_f32_16x16x32_bf16(af, bf[ni], acc[mi][ni], 0, 0, 0);
    }
    __builtin_amdgcn_s_setprio(0);
    __syncthreads();
    cur ^= 1;
  }
#undef STAGE

  // ---- epilogue ----
  const int er = (lane >> 4) * 4;
  const int ec = lane & 15;
  float bvv[4];
#pragma unroll
  for (int ni = 0; ni < 4; ++ni)
    bvv[ni] = bias ? bias[z * sBias + n0 + wn * 64 + ni * 16 + ec] : 0.0f;
  if (MODE == 0) {
    // bf16 coalesced via LDS transpose: 2 passes x 128 rows, stride 136 u16
    u16* Ep = (u16*)lds;
    u16* Cp = (u16*)Cout + z * sC;
#pragma unroll
    for (int p = 0; p < 2; ++p) {
      __syncthreads();
      if (wm == p) {
#pragma unroll
        for (int mi = 0; mi < 8; ++mi) {
#pragma unroll
          for (int i = 0; i < 4; ++i) {
            int lrow = mi * 16 + er + i;  // 0..127 within this half
            float rv = 1.0f;
            if (!EXPO && rsc) rv = rsc[z * 2048 + m0 + wm * 128 + lrow];
            float rs = 0.f;
#pragma unroll
            for (int ni = 0; ni < 4; ++ni) {
              float val = acc[mi][ni][i] * scale + bvv[ni];
              if (EXPO) { val = __expf(val); rs += val; }
              else val *= rv;
              Ep[lrow * 136 + wn * 64 + ni * 16 + ec] = f2bf(val);
            }
            if (EXPO) {
              rs += __shfl_xor(rs, 1);
              rs += __shfl_xor(rs, 2);
              rs += __shfl_xor(rs, 4);
              rs += __shfl_xor(rs, 8);
              if (ec == 0)
                psum[((long)z * 2048 + m0 + wm * 128 + lrow) * 32 + by * 2 + wn] = rs;
            }
          }
        }
      }
      __syncthreads();
#pragma unroll
      for (int s = 0; s < 8; ++s) {
        int idx = s * 256 + t;
        int R = idx >> 4;   // 0..127
        int j = idx & 15;
        u32x4 d = *(const u32x4*)(Ep + R * 136 + j * 8);
        __builtin_nontemporal_store(
            d, (u32x4*)(Cp + (m0 + p * 128 + R) * (long)N + n0 + j * 8));
      }
    }
  } else {
    // fp32 coalesced via LDS transpose: 4 passes x 64 rows, stride 132 f32
    float* Ep = (float*)lds;
    float* Cp = (float*)Cout + z * sC;
#pragma unroll
    for (int p = 0; p < 4; ++p) {
      __syncthreads();
      if (wm == (p >> 1)) {
#pragma unroll
        for (int mi2 = 0; mi2 < 2; ++mi2) {
#pragma unroll
          for (int mj = 0; mj < 2; ++mj) {
            int mi = (p & 1) * 4 + mi2 * 2 + mj;
            int lbase = (mi2 * 2 + mj) * 16;
#pragma unroll
            for (int i = 0; i < 4; ++i) {
              float rv = 1.0f;
              if (rsc) rv = rsc[z * 2048 + m0 + wm * 128 + (p & 1) * 64 + lbase + er + i];
#pragma unroll
              for (int ni = 0; ni < 4; ++ni)
                Ep[(lbase + er + i) * 132 + wn * 64 + ni * 16 + ec] =
                    acc[mi][ni][i] * scale * rv + bvv[ni];
            }
          }
        }
      }
      __syncthreads();
#pragma unroll
      for (int s = 0; s < 8; ++s) {
        int idx = s * 256 + t;
        int R = idx >> 5;   // 0..63
        int j = idx & 31;   // 0..31
        f32x4 d = *(const f32x4*)(Ep + R * 132 + j * 4);
        __builtin_nontemporal_store(
            d, (f32x4*)(Cp + (m0 + p * 64 + R) * (long)N + n0 + j * 4));
      }
    }
  }
}

// -------------------------------------------------------------- launch ----
extern "C" void kernel_launch(void* const* d_in, const int* in_sizes, int n_in,
                              void* d_out, int out_size, void* d_ws, size_t ws_size,
                              hipStream_t stream) {
  const float* query = (const float*)d_in[0];
  const float* key_  = (const float*)d_in[1];
  const float* Wq = (const float*)d_in[2];
  const float* bq = (const float*)d_in[3];
  const float* Wk = (const float*)d_in[4];
  const float* bk = (const float*)d_in[5];  // row-constant in scores: cancels
  const float* Wv = (const float*)d_in[6];
  const float* bv = (const float*)d_in[7];
  const float* Wo = (const float*)d_in[8];
  const float* bo = (const float*)d_in[9];
  (void)bk;
  float* out = (float*)d_out;

  const long tokE = 65536L * 512;
  const long bstride = 2048L * 512;

  // ws layout: Kb 0-64M | V2T 64-128M | qb 128-192M | weights/vecs | S
  char* ws = (char*)d_ws;
  u16* Kb   = (u16*)(ws);                     // 64 MB
  u16* V2T  = (u16*)(ws + 67108864L);         // 64 MB, per batch [512][2048]
  u16* qb   = (u16*)(ws + 134217728L);        // 64 MB
  u16* GT   = (u16*)(ws + 201326592L);        // 0.5 MB
  u16* W2T  = (u16*)(ws + 201850880L);        // 0.5 MB
  float* wv   = (float*)(ws + 202375168L);    // 2 KB
  float* c2   = (float*)(ws + 202377216L);    // 2 KB
  float* beta = (float*)(ws + 202379264L);    // 256 KB
  float* rinv = (float*)(ws + 202641408L);    // 256 KB
  char* Sbase = ws + 202903552L;

  // d_out time-share: Qb/V2tmp [0:64M) until consumed; psum [64:72M) per
  // group until rowred; PV2 writes all of d_out last (final output,
  // stream-ordered after each group's rowred consumed psum).
  u16* Qb = (u16*)d_out;
  u16* V2tmp = (u16*)d_out;
  float* psum = (float*)((char*)d_out + 67108864L);

  long s_avail = (long)ws_size - 202903552L;
  int g = (int)(s_avail / 8388608L);
  if (g < 1) g = 1;
  if (g > 16) g = 16;   // S per group <= 134 MB: stays L3-resident for PV
  if (g >= 8) g &= ~7;  // batches/dispatch multiple of 8 (XCD pin)

  // 1. casts + fused weights (betak fused into key cast)
  wveck<<<512, 256, 0, stream>>>(Wk, bq, wv);
  cast_f32_to_bf16<<<16384, 256, 0, stream>>>(query, Qb, tokE);
  castK_beta<<<16384, 256, 0, stream>>>(key_, wv, Kb, beta);
  smallGT<<<dim3(32, 32), 256, 0, stream>>>(Wk, Wq, GT);    // GT[n,c] = WkWq^T
  smallW2T<<<dim3(32, 32), 256, 0, stream>>>(Wv, Wo, W2T);  // W2T[e,k] = (WvWo)^T
  cveck<<<2, 256, 0, stream>>>(Wo, bv, bo, c2);

  // 2. q' = Q @ (Wq Wk^T)   [65536 x 512]   (frees Qb region afterwards)
  gemm<0, 0><<<256 * 4, 256, 0, stream>>>(
      Qb, GT, nullptr, 0, nullptr, nullptr, qb,
      512, 512, 0, 0, 0, 1.0f, 256, 4, 1, 0);

  // 3. V2 = Kb @ (Wv Wo)  [65536 x 512] into d_out scratch, then transpose
  gemm<0, 0><<<256 * 4, 256, 0, stream>>>(
      Kb, W2T, nullptr, 0, nullptr, nullptr, V2tmp,
      512, 512, 0, 0, 0, 1.0f, 256, 4, 1, 0);
  transB<<<dim3(64, 16, 32), 256, 0, stream>>>(V2tmp, V2T);

  // 4. attention per group:
  //    E = exp(q'.Kb^T/512 + beta) + row partials ; rinv = 1/rowsum ;
  //    out = E.V2 * rinv/2048 + c2   (fp32, final)
  for (int b0 = 0; b0 < 32; b0 += g) {
    int bc = (32 - b0 < g) ? (32 - b0) : g;
    u16* Sg = (u16*)Sbase;
    gemm<0, 1><<<8 * 16 * bc, 256, 0, stream>>>(
        qb + (long)b0 * bstride, Kb + (long)b0 * bstride,
        beta + (long)b0 * 2048, 2048, nullptr, psum, Sg, 2048, 512,
        bstride, bstride, 2048L * 2048, 1.0f / 512.0f, 8, 16, bc, 0);
    rowred<<<(bc * 2048 + 255) / 256, 256, 0, stream>>>(psum, rinv, bc * 2048);
    gemm<2, 0><<<8 * 4 * bc, 256, 0, stream>>>(
        Sg, V2T + (long)b0 * bstride, c2, 0, rinv, nullptr,
        out + (long)b0 * bstride, 512, 2048,
        2048L * 2048, bstride, bstride, 1.0f / 2048.0f, 8, 4, bc, 1);
  }
}